// Round 1
// baseline (1392.216 us; speedup 1.0000x reference)
//
#include <hip/hip_runtime.h>
#include <math.h>

#define NUM_HEADS 8
#define SEQ_L 1024
#define EPS 1e-5f

// ------------------------------------------------------------------
// Tiled fp32 GEMM: C[M,N] = A[M,K] @ B[K,N] + bias[N], optional ReLU.
// 64x64 tile per 256-thread block, 4x4 per thread, K-step 16.
// ------------------------------------------------------------------
__global__ __launch_bounds__(256) void gemm64(
    const float* __restrict__ A, const float* __restrict__ B,
    const float* __restrict__ bias, float* __restrict__ C,
    int M, int N, int K, int relu)
{
    __shared__ float As[16][68];
    __shared__ float Bs[16][68];
    const int tid = threadIdx.x;
    const int tx = tid & 15, ty = tid >> 4;
    const int row0 = blockIdx.y * 64, col0 = blockIdx.x * 64;

    float acc[4][4] = {};

    for (int k0 = 0; k0 < K; k0 += 16) {
        // A tile: 64 rows x 16 k  (transpose into As[k][m])
        {
            const int r = tid >> 2;            // 0..63
            const int kq = (tid & 3) * 4;      // 0,4,8,12
            const float4 a = *(const float4*)&A[(size_t)(row0 + r) * K + k0 + kq];
            As[kq + 0][r] = a.x; As[kq + 1][r] = a.y;
            As[kq + 2][r] = a.z; As[kq + 3][r] = a.w;
        }
        // B tile: 16 k x 64 n
        {
            const int kk = tid >> 4;           // 0..15
            const int n4 = (tid & 15) * 4;
            *(float4*)&Bs[kk][n4] = *(const float4*)&B[(size_t)(k0 + kk) * N + col0 + n4];
        }
        __syncthreads();
        #pragma unroll
        for (int kk = 0; kk < 16; ++kk) {
            const float4 a = *(const float4*)&As[kk][ty * 4];
            const float4 b = *(const float4*)&Bs[kk][tx * 4];
            acc[0][0] += a.x * b.x; acc[0][1] += a.x * b.y; acc[0][2] += a.x * b.z; acc[0][3] += a.x * b.w;
            acc[1][0] += a.y * b.x; acc[1][1] += a.y * b.y; acc[1][2] += a.y * b.z; acc[1][3] += a.y * b.w;
            acc[2][0] += a.z * b.x; acc[2][1] += a.z * b.y; acc[2][2] += a.z * b.z; acc[2][3] += a.z * b.w;
            acc[3][0] += a.w * b.x; acc[3][1] += a.w * b.y; acc[3][2] += a.w * b.z; acc[3][3] += a.w * b.w;
        }
        __syncthreads();
    }

    const float4 bv = *(const float4*)&bias[col0 + tx * 4];
    #pragma unroll
    for (int i = 0; i < 4; ++i) {
        float4 o;
        o.x = acc[i][0] + bv.x; o.y = acc[i][1] + bv.y;
        o.z = acc[i][2] + bv.z; o.w = acc[i][3] + bv.w;
        if (relu) {
            o.x = fmaxf(o.x, 0.f); o.y = fmaxf(o.y, 0.f);
            o.z = fmaxf(o.z, 0.f); o.w = fmaxf(o.w, 0.f);
        }
        *(float4*)&C[(size_t)(row0 + ty * 4 + i) * N + col0 + tx * 4] = o;
    }
}

// ------------------------------------------------------------------
// Flash-style attention. Block = 256 threads handles one (b,h) and a
// 32-row q-tile; iterates over 64-key chunks with online softmax.
// qkv layout: [B*L, 1536] (q | k | v each 512 wide, head h at h*64).
// out: [B*L, 512] with head h at h*64 (i.e. [B,L,D]).
// ------------------------------------------------------------------
__global__ __launch_bounds__(256) void attn_kernel(
    const float* __restrict__ qkv, const float* __restrict__ abias,
    const int* __restrict__ mask, float* __restrict__ out)
{
    const int bh = blockIdx.y;                // 0..63
    const int b = bh >> 3, h = bh & 7;
    const int q0 = blockIdx.x * 32;
    const int tid = threadIdx.x;
    const int r = tid >> 3;                   // q-row in tile, 0..31
    const int g = tid & 7;                    // key-group lane, 0..7

    __shared__ float Qs[32][68];
    __shared__ float Ks[64][68];
    __shared__ float Vs[64][68];
    __shared__ float Ps[32][68];

    // load Q tile, pre-scaled by 1/sqrt(dk)=0.125
    {
        const int rr = tid >> 3;
        const int d8 = (tid & 7) * 8;
        const float* src = &qkv[(size_t)(b * SEQ_L + q0 + rr) * 1536 + h * 64 + d8];
        const float4 x0 = *(const float4*)src;
        const float4 x1 = *(const float4*)(src + 4);
        const float s = 0.125f;
        Qs[rr][d8 + 0] = x0.x * s; Qs[rr][d8 + 1] = x0.y * s;
        Qs[rr][d8 + 2] = x0.z * s; Qs[rr][d8 + 3] = x0.w * s;
        Qs[rr][d8 + 4] = x1.x * s; Qs[rr][d8 + 5] = x1.y * s;
        Qs[rr][d8 + 6] = x1.z * s; Qs[rr][d8 + 7] = x1.w * s;
    }

    float o[8] = {};
    float m = -1e30f, l = 0.f;

    for (int k0 = 0; k0 < SEQ_L; k0 += 64) {
        __syncthreads();   // protect Ks/Vs/Ps (and Qs on first iter)
        // load K and V chunks: 64 keys x 64 dims each
        {
            const int j = tid >> 2;            // 0..63
            const int d16 = (tid & 3) * 16;
            const float* kp = &qkv[(size_t)(b * SEQ_L + k0 + j) * 1536 + 512 + h * 64 + d16];
            const float* vp = kp + 512;
            #pragma unroll
            for (int q = 0; q < 4; ++q) {
                *(float4*)&Ks[j][d16 + q * 4] = *(const float4*)(kp + q * 4);
                *(float4*)&Vs[j][d16 + q * 4] = *(const float4*)(vp + q * 4);
            }
        }
        __syncthreads();

        // scores for 8 keys: j = g + 8*i
        float sc[8];
        #pragma unroll
        for (int i = 0; i < 8; ++i) {
            const int j = g + 8 * i;
            float dot = 0.f;
            #pragma unroll
            for (int dq = 0; dq < 16; ++dq) {
                const float4 qv = *(const float4*)&Qs[r][dq * 4];
                const float4 kv = *(const float4*)&Ks[j][dq * 4];
                dot += qv.x * kv.x + qv.y * kv.y + qv.z * kv.z + qv.w * kv.w;
            }
            const float bb = abias[((size_t)(b * NUM_HEADS + h) * SEQ_L + (q0 + r)) * SEQ_L + k0 + j];
            sc[i] = (mask[b * SEQ_L + k0 + j] > 0) ? (dot + bb) : -1e30f;
        }
        // chunk max (over 64 keys = own 8 then 8-thread group reduce)
        float cmax = sc[0];
        #pragma unroll
        for (int i = 1; i < 8; ++i) cmax = fmaxf(cmax, sc[i]);
        #pragma unroll
        for (int off = 1; off < 8; off <<= 1)
            cmax = fmaxf(cmax, __shfl_xor(cmax, off, 64));

        const float mnew = fmaxf(m, cmax);
        const float scale = __expf(m - mnew);
        float p[8];
        float lsum = 0.f;
        #pragma unroll
        for (int i = 0; i < 8; ++i) {
            p[i] = (sc[i] > -1e29f) ? __expf(sc[i] - mnew) : 0.f;
            lsum += p[i];
        }
        #pragma unroll
        for (int off = 1; off < 8; off <<= 1)
            lsum += __shfl_xor(lsum, off, 64);
        l = l * scale + lsum;
        m = mnew;
        #pragma unroll
        for (int i = 0; i < 8; ++i) Ps[r][g + 8 * i] = p[i];
        #pragma unroll
        for (int i = 0; i < 8; ++i) o[i] *= scale;
        __syncthreads();

        // PV: o[d] += sum_j P[r][j] * V[j][d], d = g*8 + i
        #pragma unroll
        for (int j = 0; j < 64; ++j) {
            const float pv = Ps[r][j];
            const float4 v0 = *(const float4*)&Vs[j][g * 8];
            const float4 v1 = *(const float4*)&Vs[j][g * 8 + 4];
            o[0] += pv * v0.x; o[1] += pv * v0.y; o[2] += pv * v0.z; o[3] += pv * v0.w;
            o[4] += pv * v1.x; o[5] += pv * v1.y; o[6] += pv * v1.z; o[7] += pv * v1.w;
        }
    }

    const float inv = (l > 0.f) ? (1.0f / l) : 0.f;
    float* dst = &out[(size_t)(b * SEQ_L + q0 + r) * 512 + h * 64 + g * 8];
    float4 o0, o1;
    o0.x = o[0] * inv; o0.y = o[1] * inv; o0.z = o[2] * inv; o0.w = o[3] * inv;
    o1.x = o[4] * inv; o1.y = o[5] * inv; o1.z = o[6] * inv; o1.w = o[7] * inv;
    *(float4*)dst = o0;
    *(float4*)(dst + 4) = o1;
}

// ------------------------------------------------------------------
// out[row] = LayerNorm(X[row] + Y[row]) * gamma + beta.  One wave per
// row (D=512 -> 8 floats/lane), 4 rows per 256-thread block.
// ------------------------------------------------------------------
__global__ __launch_bounds__(256) void add_ln_kernel(
    const float* __restrict__ X, const float* __restrict__ Y,
    const float* __restrict__ gamma, const float* __restrict__ beta,
    float* __restrict__ out)
{
    const int wave = threadIdx.x >> 6;
    const int lane = threadIdx.x & 63;
    const int row = blockIdx.x * 4 + wave;
    const float* xp = X + (size_t)row * 512 + lane * 8;
    const float* yp = Y + (size_t)row * 512 + lane * 8;

    float v[8];
    const float4 a0 = *(const float4*)xp;
    const float4 a1 = *(const float4*)(xp + 4);
    const float4 b0 = *(const float4*)yp;
    const float4 b1 = *(const float4*)(yp + 4);
    v[0] = a0.x + b0.x; v[1] = a0.y + b0.y; v[2] = a0.z + b0.z; v[3] = a0.w + b0.w;
    v[4] = a1.x + b1.x; v[5] = a1.y + b1.y; v[6] = a1.z + b1.z; v[7] = a1.w + b1.w;

    float s = 0.f, sq = 0.f;
    #pragma unroll
    for (int i = 0; i < 8; ++i) { s += v[i]; sq += v[i] * v[i]; }
    #pragma unroll
    for (int off = 1; off < 64; off <<= 1) {
        s += __shfl_xor(s, off, 64);
        sq += __shfl_xor(sq, off, 64);
    }
    const float mu = s * (1.f / 512.f);
    const float var = sq * (1.f / 512.f) - mu * mu;
    const float rstd = rsqrtf(var + EPS);

    float* op = out + (size_t)row * 512 + lane * 8;
    const float4 g0 = *(const float4*)&gamma[lane * 8];
    const float4 g1 = *(const float4*)&gamma[lane * 8 + 4];
    const float4 e0 = *(const float4*)&beta[lane * 8];
    const float4 e1 = *(const float4*)&beta[lane * 8 + 4];
    float4 r0, r1;
    r0.x = (v[0] - mu) * rstd * g0.x + e0.x;
    r0.y = (v[1] - mu) * rstd * g0.y + e0.y;
    r0.z = (v[2] - mu) * rstd * g0.z + e0.z;
    r0.w = (v[3] - mu) * rstd * g0.w + e0.w;
    r1.x = (v[4] - mu) * rstd * g1.x + e1.x;
    r1.y = (v[5] - mu) * rstd * g1.y + e1.y;
    r1.z = (v[6] - mu) * rstd * g1.z + e1.z;
    r1.w = (v[7] - mu) * rstd * g1.w + e1.w;
    *(float4*)op = r0;
    *(float4*)(op + 4) = r1;
}

// ------------------------------------------------------------------
extern "C" void kernel_launch(void* const* d_in, const int* in_sizes, int n_in,
                              void* d_out, int out_size, void* d_ws, size_t ws_size,
                              hipStream_t stream)
{
    const float* h    = (const float*)d_in[0];
    const float* ab   = (const float*)d_in[1];
    const int*   mask = (const int*)d_in[2];
    const float* Wqkv = (const float*)d_in[3];
    const float* bqkv = (const float*)d_in[4];
    const float* Wo   = (const float*)d_in[5];
    const float* bo   = (const float*)d_in[6];
    const float* W1   = (const float*)d_in[7];
    const float* b1   = (const float*)d_in[8];
    const float* W2   = (const float*)d_in[9];
    const float* b2   = (const float*)d_in[10];
    const float* g1   = (const float*)d_in[11];
    const float* be1  = (const float*)d_in[12];
    const float* g2   = (const float*)d_in[13];
    const float* be2  = (const float*)d_in[14];
    float* out = (float*)d_out;
    char* ws = (char*)d_ws;

    const int M = 8 * 1024;  // 8192 rows

    // workspace layout (regions reused once producer/consumer are done):
    float* qkv      = (float*)(ws);                              // [M,1536] 48MB (dead after attn)
    float* attn_out = (float*)(ws + (size_t)48 * 1024 * 1024);   // [M,512]  16MB (dead after proj)
    float* proj     = (float*)(ws);                              // [M,512]  16MB (dead after LN1)
    float* h1       = (float*)(ws + (size_t)16 * 1024 * 1024);   // [M,512]  16MB (kept for resid2)
    float* ff       = (float*)(ws + (size_t)32 * 1024 * 1024);   // [M,2048] 64MB
    float* f2       = (float*)(ws);                              // [M,512]  16MB

    // 1. QKV GEMM: [8192,512] @ [512,1536]
    gemm64<<<dim3(1536 / 64, M / 64), 256, 0, stream>>>(h, Wqkv, bqkv, qkv, M, 1536, 512, 0);
    // 2. attention
    attn_kernel<<<dim3(SEQ_L / 32, 64), 256, 0, stream>>>(qkv, ab, mask, attn_out);
    // 3. output projection: [8192,512] @ [512,512]
    gemm64<<<dim3(512 / 64, M / 64), 256, 0, stream>>>(attn_out, Wo, bo, proj, M, 512, 512, 0);
    // 4. h1 = LN(h + proj)
    add_ln_kernel<<<dim3(M / 4), 256, 0, stream>>>(h, proj, g1, be1, h1);
    // 5. ff = relu(h1 @ W1 + b1): [8192,512] @ [512,2048]
    gemm64<<<dim3(2048 / 64, M / 64), 256, 0, stream>>>(h1, W1, b1, ff, M, 2048, 512, 1);
    // 6. f2 = ff @ W2 + b2: [8192,2048] @ [2048,512]
    gemm64<<<dim3(512 / 64, M / 64), 256, 0, stream>>>(ff, W2, b2, f2, M, 512, 2048, 0);
    // 7. out = LN(h1 + f2)
    add_ln_kernel<<<dim3(M / 4), 256, 0, stream>>>(h1, f2, g2, be2, out);
}

// Round 2
// 762.187 us; speedup vs baseline: 1.8266x; 1.8266x over previous
//
#include <hip/hip_runtime.h>
#include <hip/hip_bf16.h>
#include <math.h>

#define NUM_HEADS 8
#define SEQ_L 1024
#define EPS 1e-5f

typedef __bf16 bf16x8 __attribute__((ext_vector_type(8)));
typedef float f32x4 __attribute__((ext_vector_type(4)));
typedef __hip_bfloat16 bf16;

#define AS1 __attribute__((address_space(1)))
#define AS3 __attribute__((address_space(3)))

__device__ __forceinline__ void gload_lds16(const void* g, void* l) {
    __builtin_amdgcn_global_load_lds((const AS1 unsigned*)g, (AS3 unsigned*)l, 16, 0, 0);
}

// ------------------------------------------------------------------
// fp32 -> bf16 elementwise convert (n divisible by 4)
// ------------------------------------------------------------------
__global__ __launch_bounds__(256) void f32_to_bf16_kernel(
    const float* __restrict__ in, bf16* __restrict__ out, int n)
{
    const int i = (blockIdx.x * 256 + threadIdx.x) * 4;
    if (i >= n) return;
    const float4 v = *(const float4*)&in[i];
    out[i + 0] = __float2bfloat16(v.x);
    out[i + 1] = __float2bfloat16(v.y);
    out[i + 2] = __float2bfloat16(v.z);
    out[i + 3] = __float2bfloat16(v.w);
}

// ------------------------------------------------------------------
// W[K][N] fp32 -> Wt[N][K] bf16 (K,N divisible by 32)
// ------------------------------------------------------------------
__global__ __launch_bounds__(256) void transpose_w(
    const float* __restrict__ W, bf16* __restrict__ Wt, int K, int N)
{
    __shared__ float t[32][33];
    const int tx = threadIdx.x & 31, ty = threadIdx.x >> 5;   // ty 0..7
    const int n0 = blockIdx.x * 32, k0 = blockIdx.y * 32;
    #pragma unroll
    for (int r = 0; r < 4; ++r)
        t[ty + 8 * r][tx] = W[(size_t)(k0 + ty + 8 * r) * N + n0 + tx];
    __syncthreads();
    #pragma unroll
    for (int r = 0; r < 4; ++r)
        Wt[(size_t)(n0 + ty + 8 * r) * K + k0 + tx] = __float2bfloat16(t[tx][ty + 8 * r]);
}

// ------------------------------------------------------------------
// bf16 MFMA GEMM (m97 structure): C[M,N] = A[M,K] @ Bt[N,K]^T + bias.
// 128x128 tile / 256 threads (4 waves, 2x2), BK=32, 16x16x32 MFMA.
// A row-major [M][K] bf16, Bt row-major [N][K] bf16 (i.e. B^T).
// Outputs: fp32 C (optional), bf16 Cb (optional), optional ReLU.
// ------------------------------------------------------------------
__global__ __launch_bounds__(256) void gemm_bf16(
    const bf16* __restrict__ A, const bf16* __restrict__ Bt,
    const float* __restrict__ bias,
    float* __restrict__ C, bf16* __restrict__ Cb,
    int M, int N, int K, int relu)
{
    __shared__ __align__(16) bf16 Abuf[128 * 32];
    __shared__ __align__(16) bf16 Bbuf[128 * 32];
    const int tid = threadIdx.x;
    const int wv = tid >> 6, lane = tid & 63;
    const int row0 = blockIdx.y * 128, col0 = blockIdx.x * 128;
    const int wm = (wv >> 1) * 64, wn = (wv & 1) * 64;
    const int r0 = lane & 15, kb = lane >> 4;

    f32x4 acc[4][4] = {};

    const int arow = lane >> 2;          // 0..15 within 16-row chunk
    const int akoff = (lane & 3) * 8;    // k element offset (8 bf16 = 16B)

    for (int k0 = 0; k0 < K; k0 += 32) {
        #pragma unroll
        for (int s = 0; s < 2; ++s) {
            const int c = 2 * wv + s;    // chunk 0..7 (16 rows each)
            gload_lds16(&A[(size_t)(row0 + c * 16 + arow) * K + k0 + akoff],
                        &Abuf[c * 512]);
            gload_lds16(&Bt[(size_t)(col0 + c * 16 + arow) * K + k0 + akoff],
                        &Bbuf[c * 512]);
        }
        __syncthreads();   // drains vmcnt -> LDS tiles ready

        bf16x8 a[4], b[4];
        #pragma unroll
        for (int i = 0; i < 4; ++i)
            a[i] = *(const bf16x8*)&Abuf[(wm + i * 16 + r0) * 32 + kb * 8];
        #pragma unroll
        for (int j = 0; j < 4; ++j)
            b[j] = *(const bf16x8*)&Bbuf[(wn + j * 16 + r0) * 32 + kb * 8];
        #pragma unroll
        for (int i = 0; i < 4; ++i)
            #pragma unroll
            for (int j = 0; j < 4; ++j)
                acc[i][j] = __builtin_amdgcn_mfma_f32_16x16x32_bf16(a[i], b[j], acc[i][j], 0, 0, 0);
        __syncthreads();
    }

    // epilogue: C row = (lane>>4)*4 + reg, col = lane&15 within fragment
    float bv[4];
    #pragma unroll
    for (int j = 0; j < 4; ++j) bv[j] = bias[col0 + wn + j * 16 + r0];

    #pragma unroll
    for (int i = 0; i < 4; ++i) {
        #pragma unroll
        for (int j = 0; j < 4; ++j) {
            const int col = col0 + wn + j * 16 + r0;
            #pragma unroll
            for (int reg = 0; reg < 4; ++reg) {
                const int row = row0 + wm + i * 16 + kb * 4 + reg;
                float v = acc[i][j][reg] + bv[j];
                if (relu) v = fmaxf(v, 0.f);
                if (C)  C[(size_t)row * N + col] = v;
                if (Cb) Cb[(size_t)row * N + col] = __float2bfloat16(v);
            }
        }
    }
}

// ------------------------------------------------------------------
// Flash-style attention (fp32). Block = 256 threads handles one (b,h)
// and a 32-row q-tile; 64-key chunks with online softmax.
// qkv layout: [B*L, 1536] (q | k | v, head h at h*64). out: bf16 [B*L,512].
// ------------------------------------------------------------------
__global__ __launch_bounds__(256) void attn_kernel(
    const float* __restrict__ qkv, const float* __restrict__ abias,
    const int* __restrict__ mask, bf16* __restrict__ out)
{
    const int bh = blockIdx.y;                // 0..63
    const int b = bh >> 3, h = bh & 7;
    const int q0 = blockIdx.x * 32;
    const int tid = threadIdx.x;
    const int r = tid >> 3;                   // q-row in tile, 0..31
    const int g = tid & 7;                    // key-group lane, 0..7

    __shared__ float Qs[32][68];
    __shared__ float Ks[64][68];
    __shared__ float Vs[64][68];
    __shared__ float Ps[32][68];

    {
        const int rr = tid >> 3;
        const int d8 = (tid & 7) * 8;
        const float* src = &qkv[(size_t)(b * SEQ_L + q0 + rr) * 1536 + h * 64 + d8];
        const float4 x0 = *(const float4*)src;
        const float4 x1 = *(const float4*)(src + 4);
        const float s = 0.125f;
        Qs[rr][d8 + 0] = x0.x * s; Qs[rr][d8 + 1] = x0.y * s;
        Qs[rr][d8 + 2] = x0.z * s; Qs[rr][d8 + 3] = x0.w * s;
        Qs[rr][d8 + 4] = x1.x * s; Qs[rr][d8 + 5] = x1.y * s;
        Qs[rr][d8 + 6] = x1.z * s; Qs[rr][d8 + 7] = x1.w * s;
    }

    float o[8] = {};
    float m = -1e30f, l = 0.f;

    for (int k0 = 0; k0 < SEQ_L; k0 += 64) {
        __syncthreads();
        {
            const int j = tid >> 2;            // 0..63
            const int d16 = (tid & 3) * 16;
            const float* kp = &qkv[(size_t)(b * SEQ_L + k0 + j) * 1536 + 512 + h * 64 + d16];
            const float* vp = kp + 512;
            #pragma unroll
            for (int q = 0; q < 4; ++q) {
                *(float4*)&Ks[j][d16 + q * 4] = *(const float4*)(kp + q * 4);
                *(float4*)&Vs[j][d16 + q * 4] = *(const float4*)(vp + q * 4);
            }
        }
        __syncthreads();

        float sc[8];
        #pragma unroll
        for (int i = 0; i < 8; ++i) {
            const int j = g + 8 * i;
            float dot = 0.f;
            #pragma unroll
            for (int dq = 0; dq < 16; ++dq) {
                const float4 qv = *(const float4*)&Qs[r][dq * 4];
                const float4 kv = *(const float4*)&Ks[j][dq * 4];
                dot += qv.x * kv.x + qv.y * kv.y + qv.z * kv.z + qv.w * kv.w;
            }
            const float bb = abias[((size_t)(b * NUM_HEADS + h) * SEQ_L + (q0 + r)) * SEQ_L + k0 + j];
            sc[i] = (mask[b * SEQ_L + k0 + j] > 0) ? (dot + bb) : -1e30f;
        }
        float cmax = sc[0];
        #pragma unroll
        for (int i = 1; i < 8; ++i) cmax = fmaxf(cmax, sc[i]);
        #pragma unroll
        for (int off = 1; off < 8; off <<= 1)
            cmax = fmaxf(cmax, __shfl_xor(cmax, off, 64));

        const float mnew = fmaxf(m, cmax);
        const float scale = __expf(m - mnew);
        float p[8];
        float lsum = 0.f;
        #pragma unroll
        for (int i = 0; i < 8; ++i) {
            p[i] = (sc[i] > -1e29f) ? __expf(sc[i] - mnew) : 0.f;
            lsum += p[i];
        }
        #pragma unroll
        for (int off = 1; off < 8; off <<= 1)
            lsum += __shfl_xor(lsum, off, 64);
        l = l * scale + lsum;
        m = mnew;
        #pragma unroll
        for (int i = 0; i < 8; ++i) Ps[r][g + 8 * i] = p[i];
        #pragma unroll
        for (int i = 0; i < 8; ++i) o[i] *= scale;
        __syncthreads();

        #pragma unroll
        for (int j = 0; j < 64; ++j) {
            const float pv = Ps[r][j];
            const float4 v0 = *(const float4*)&Vs[j][g * 8];
            const float4 v1 = *(const float4*)&Vs[j][g * 8 + 4];
            o[0] += pv * v0.x; o[1] += pv * v0.y; o[2] += pv * v0.z; o[3] += pv * v0.w;
            o[4] += pv * v1.x; o[5] += pv * v1.y; o[6] += pv * v1.z; o[7] += pv * v1.w;
        }
    }

    const float inv = (l > 0.f) ? (1.0f / l) : 0.f;
    bf16* dst = &out[(size_t)(b * SEQ_L + q0 + r) * 512 + h * 64 + g * 8];
    #pragma unroll
    for (int i = 0; i < 8; ++i) dst[i] = __float2bfloat16(o[i] * inv);
}

// ------------------------------------------------------------------
// out = LayerNorm(X + Y) * gamma + beta; optional bf16 copy.
// ------------------------------------------------------------------
__global__ __launch_bounds__(256) void add_ln_kernel(
    const float* __restrict__ X, const float* __restrict__ Y,
    const float* __restrict__ gamma, const float* __restrict__ beta,
    float* __restrict__ out, bf16* __restrict__ outb)
{
    const int wave = threadIdx.x >> 6;
    const int lane = threadIdx.x & 63;
    const int row = blockIdx.x * 4 + wave;
    const float* xp = X + (size_t)row * 512 + lane * 8;
    const float* yp = Y + (size_t)row * 512 + lane * 8;

    float v[8];
    const float4 a0 = *(const float4*)xp;
    const float4 a1 = *(const float4*)(xp + 4);
    const float4 b0 = *(const float4*)yp;
    const float4 b1 = *(const float4*)(yp + 4);
    v[0] = a0.x + b0.x; v[1] = a0.y + b0.y; v[2] = a0.z + b0.z; v[3] = a0.w + b0.w;
    v[4] = a1.x + b1.x; v[5] = a1.y + b1.y; v[6] = a1.z + b1.z; v[7] = a1.w + b1.w;

    float s = 0.f, sq = 0.f;
    #pragma unroll
    for (int i = 0; i < 8; ++i) { s += v[i]; sq += v[i] * v[i]; }
    #pragma unroll
    for (int off = 1; off < 64; off <<= 1) {
        s += __shfl_xor(s, off, 64);
        sq += __shfl_xor(sq, off, 64);
    }
    const float mu = s * (1.f / 512.f);
    const float var = sq * (1.f / 512.f) - mu * mu;
    const float rstd = rsqrtf(var + EPS);

    const int c = lane * 8;
    const float4 g0 = *(const float4*)&gamma[c];
    const float4 g1 = *(const float4*)&gamma[c + 4];
    const float4 e0 = *(const float4*)&beta[c];
    const float4 e1 = *(const float4*)&beta[c + 4];
    float r[8];
    r[0] = (v[0] - mu) * rstd * g0.x + e0.x;
    r[1] = (v[1] - mu) * rstd * g0.y + e0.y;
    r[2] = (v[2] - mu) * rstd * g0.z + e0.z;
    r[3] = (v[3] - mu) * rstd * g0.w + e0.w;
    r[4] = (v[4] - mu) * rstd * g1.x + e1.x;
    r[5] = (v[5] - mu) * rstd * g1.y + e1.y;
    r[6] = (v[6] - mu) * rstd * g1.z + e1.z;
    r[7] = (v[7] - mu) * rstd * g1.w + e1.w;

    float* op = out + (size_t)row * 512 + c;
    *(float4*)op = make_float4(r[0], r[1], r[2], r[3]);
    *(float4*)(op + 4) = make_float4(r[4], r[5], r[6], r[7]);
    if (outb) {
        bf16* ob = outb + (size_t)row * 512 + c;
        #pragma unroll
        for (int i = 0; i < 8; ++i) ob[i] = __float2bfloat16(r[i]);
    }
}

// ------------------------------------------------------------------
extern "C" void kernel_launch(void* const* d_in, const int* in_sizes, int n_in,
                              void* d_out, int out_size, void* d_ws, size_t ws_size,
                              hipStream_t stream)
{
    const float* h    = (const float*)d_in[0];
    const float* ab   = (const float*)d_in[1];
    const int*   mask = (const int*)d_in[2];
    const float* Wqkv = (const float*)d_in[3];
    const float* bqkv = (const float*)d_in[4];
    const float* Wo   = (const float*)d_in[5];
    const float* bo   = (const float*)d_in[6];
    const float* W1   = (const float*)d_in[7];
    const float* b1   = (const float*)d_in[8];
    const float* W2   = (const float*)d_in[9];
    const float* b2   = (const float*)d_in[10];
    const float* g1   = (const float*)d_in[11];
    const float* be1  = (const float*)d_in[12];
    const float* g2   = (const float*)d_in[13];
    const float* be2  = (const float*)d_in[14];
    float* out = (float*)d_out;
    char* ws = (char*)d_ws;

    const int M = 8 * 1024;
    const size_t MB = 1024 * 1024;

    // workspace layout (liveness-based reuse):
    bf16*  hb   = (bf16*)(ws + 0 * MB);    // [M,512]   8MB  (dead after QKV gemm)
    bf16*  Wtq  = (bf16*)(ws + 8 * MB);    // [1536,512] 1.5MB (persist)
    bf16*  Wto  = (bf16*)(ws + 10 * MB);   // [512,512]  0.5MB
    bf16*  Wt1  = (bf16*)(ws + 11 * MB);   // [2048,512] 2MB
    bf16*  Wt2  = (bf16*)(ws + 13 * MB);   // [512,2048] 2MB
    float* qkv  = (float*)(ws + 15 * MB);  // [M,1536]  48MB (dead after attn)
    bf16*  aob  = (bf16*)(ws + 63 * MB);   // [M,512]    8MB (dead after proj)
    float* proj = (float*)(ws + 15 * MB);  // [M,512]   16MB (reuses qkv region)
    float* h1   = (float*)(ws + 31 * MB);  // [M,512]   16MB
    bf16*  h1b  = (bf16*)(ws + 47 * MB);   // [M,512]    8MB
    bf16*  ffb  = (bf16*)(ws + 55 * MB);   // [M,2048]  32MB
    float* f2   = (float*)(ws + 0 * MB);   // [M,512]   16MB (reuses hb region)

    // 0. convert h and weights to bf16 (weights transposed to [N][K])
    f32_to_bf16_kernel<<<dim3(M * 512 / 1024), 256, 0, stream>>>(h, hb, M * 512);
    transpose_w<<<dim3(1536 / 32, 512 / 32), 256, 0, stream>>>(Wqkv, Wtq, 512, 1536);
    transpose_w<<<dim3(512 / 32, 512 / 32), 256, 0, stream>>>(Wo, Wto, 512, 512);
    transpose_w<<<dim3(2048 / 32, 512 / 32), 256, 0, stream>>>(W1, Wt1, 512, 2048);
    transpose_w<<<dim3(512 / 32, 2048 / 32), 256, 0, stream>>>(W2, Wt2, 2048, 512);

    // 1. QKV: [8192,512] @ [512,1536] -> fp32
    gemm_bf16<<<dim3(1536 / 128, M / 128), 256, 0, stream>>>(hb, Wtq, bqkv, qkv, nullptr, M, 1536, 512, 0);
    // 2. attention -> bf16
    attn_kernel<<<dim3(SEQ_L / 32, 64), 256, 0, stream>>>(qkv, ab, mask, aob);
    // 3. proj: [8192,512] @ [512,512] -> fp32
    gemm_bf16<<<dim3(512 / 128, M / 128), 256, 0, stream>>>(aob, Wto, bo, proj, nullptr, M, 512, 512, 0);
    // 4. h1 = LN(h + proj) -> fp32 + bf16
    add_ln_kernel<<<dim3(M / 4), 256, 0, stream>>>(h, proj, g1, be1, h1, h1b);
    // 5. ff = relu(h1 @ W1 + b1) -> bf16 only
    gemm_bf16<<<dim3(2048 / 128, M / 128), 256, 0, stream>>>(h1b, Wt1, b1, nullptr, ffb, M, 2048, 512, 1);
    // 6. f2 = ff @ W2 + b2 -> fp32
    gemm_bf16<<<dim3(512 / 128, M / 128), 256, 0, stream>>>(ffb, Wt2, b2, f2, nullptr, M, 512, 2048, 0);
    // 7. out = LN(h1 + f2)
    add_ln_kernel<<<dim3(M / 4), 256, 0, stream>>>(h1, f2, g2, be2, out, nullptr);
}

// Round 3
// 268.303 us; speedup vs baseline: 5.1890x; 2.8408x over previous
//
#include <hip/hip_runtime.h>
#include <hip/hip_bf16.h>
#include <math.h>

#define NUM_HEADS 8
#define SEQ_L 1024
#define EPS 1e-5f
#define KVBLK 64

typedef __bf16 bf16x8 __attribute__((ext_vector_type(8)));
typedef float f32x4 __attribute__((ext_vector_type(4)));
typedef __hip_bfloat16 bf16;

#define AS1 __attribute__((address_space(1)))
#define AS3 __attribute__((address_space(3)))

__device__ __forceinline__ void gload_lds16(const void* g, void* l) {
    __builtin_amdgcn_global_load_lds((const AS1 unsigned*)g, (AS3 unsigned*)l, 16, 0, 0);
}

__device__ __forceinline__ unsigned short bfb(float x) {
    bf16 b = __float2bfloat16(x);
    return *(unsigned short*)&b;
}

// swizzle for [R][64] bf16 LDS tiles: byte ^= ((row&7)<<4)  ==  elem ^= ((row&7)<<3)
__device__ __forceinline__ int swz64(int el, int row) { return el ^ ((row & 7) << 3); }

// ------------------------------------------------------------------
// fp32 -> bf16 elementwise convert (n divisible by 4)
// ------------------------------------------------------------------
__global__ __launch_bounds__(256) void f32_to_bf16_kernel(
    const float* __restrict__ in, bf16* __restrict__ out, int n)
{
    const int i = (blockIdx.x * 256 + threadIdx.x) * 4;
    if (i >= n) return;
    const float4 v = *(const float4*)&in[i];
    out[i + 0] = __float2bfloat16(v.x);
    out[i + 1] = __float2bfloat16(v.y);
    out[i + 2] = __float2bfloat16(v.z);
    out[i + 3] = __float2bfloat16(v.w);
}

// ------------------------------------------------------------------
// W[K][N] fp32 -> Wt[N][K] bf16 (K,N divisible by 32)
// ------------------------------------------------------------------
__global__ __launch_bounds__(256) void transpose_w(
    const float* __restrict__ W, bf16* __restrict__ Wt, int K, int N)
{
    __shared__ float t[32][33];
    const int tx = threadIdx.x & 31, ty = threadIdx.x >> 5;   // ty 0..7
    const int n0 = blockIdx.x * 32, k0 = blockIdx.y * 32;
    #pragma unroll
    for (int r = 0; r < 4; ++r)
        t[ty + 8 * r][tx] = W[(size_t)(k0 + ty + 8 * r) * N + n0 + tx];
    __syncthreads();
    #pragma unroll
    for (int r = 0; r < 4; ++r)
        Wt[(size_t)(n0 + ty + 8 * r) * K + k0 + tx] = __float2bfloat16(t[tx][ty + 8 * r]);
}

// ------------------------------------------------------------------
// bf16 MFMA GEMM (m97 structure): C[M,N] = A[M,K] @ Bt[N,K]^T + bias.
// 128x128 tile / 256 threads (4 waves 2x2), BK=32, 16x16x32 MFMA.
// ------------------------------------------------------------------
__global__ __launch_bounds__(256) void gemm_bf16(
    const bf16* __restrict__ A, const bf16* __restrict__ Bt,
    const float* __restrict__ bias,
    float* __restrict__ C, bf16* __restrict__ Cb,
    int M, int N, int K, int relu)
{
    __shared__ __align__(16) bf16 Abuf[128 * 32];
    __shared__ __align__(16) bf16 Bbuf[128 * 32];
    const int tid = threadIdx.x;
    const int wv = tid >> 6, lane = tid & 63;
    const int row0 = blockIdx.y * 128, col0 = blockIdx.x * 128;
    const int wm = (wv >> 1) * 64, wn = (wv & 1) * 64;
    const int r0 = lane & 15, kb = lane >> 4;

    f32x4 acc[4][4] = {};
    const int arow = lane >> 2;
    const int akoff = (lane & 3) * 8;

    for (int k0 = 0; k0 < K; k0 += 32) {
        #pragma unroll
        for (int s = 0; s < 2; ++s) {
            const int c = 2 * wv + s;
            gload_lds16(&A[(size_t)(row0 + c * 16 + arow) * K + k0 + akoff], &Abuf[c * 512]);
            gload_lds16(&Bt[(size_t)(col0 + c * 16 + arow) * K + k0 + akoff], &Bbuf[c * 512]);
        }
        __syncthreads();

        bf16x8 a[4], b[4];
        #pragma unroll
        for (int i = 0; i < 4; ++i)
            a[i] = *(const bf16x8*)&Abuf[(wm + i * 16 + r0) * 32 + kb * 8];
        #pragma unroll
        for (int j = 0; j < 4; ++j)
            b[j] = *(const bf16x8*)&Bbuf[(wn + j * 16 + r0) * 32 + kb * 8];
        #pragma unroll
        for (int i = 0; i < 4; ++i)
            #pragma unroll
            for (int j = 0; j < 4; ++j)
                acc[i][j] = __builtin_amdgcn_mfma_f32_16x16x32_bf16(a[i], b[j], acc[i][j], 0, 0, 0);
        __syncthreads();
    }

    float bv[4];
    #pragma unroll
    for (int j = 0; j < 4; ++j) bv[j] = bias[col0 + wn + j * 16 + r0];

    #pragma unroll
    for (int i = 0; i < 4; ++i) {
        #pragma unroll
        for (int j = 0; j < 4; ++j) {
            const int col = col0 + wn + j * 16 + r0;
            #pragma unroll
            for (int reg = 0; reg < 4; ++reg) {
                const int row = row0 + wm + i * 16 + kb * 4 + reg;
                float v = acc[i][j][reg] + bv[j];
                if (relu) v = fmaxf(v, 0.f);
                if (C)  C[(size_t)row * N + col] = v;
                if (Cb) Cb[(size_t)row * N + col] = __float2bfloat16(v);
            }
        }
    }
}

// ------------------------------------------------------------------
// QKV GEMM: [M,512] @ [512,1536] with split epilogue ->
//   Qb[bh][L][64] bf16 (scaled 0.125), Kb[bh][L][64], Vtb[bh][64][L].
// ------------------------------------------------------------------
__global__ __launch_bounds__(256) void gemm_qkv(
    const bf16* __restrict__ A, const bf16* __restrict__ Bt,
    const float* __restrict__ bias,
    bf16* __restrict__ Qb, bf16* __restrict__ Kb, bf16* __restrict__ Vtb,
    int M, int N, int K)
{
    __shared__ __align__(16) bf16 Abuf[128 * 32];
    __shared__ __align__(16) bf16 Bbuf[128 * 32];
    const int tid = threadIdx.x;
    const int wv = tid >> 6, lane = tid & 63;
    const int row0 = blockIdx.y * 128, col0 = blockIdx.x * 128;
    const int wm = (wv >> 1) * 64, wn = (wv & 1) * 64;
    const int r0 = lane & 15, kb = lane >> 4;

    f32x4 acc[4][4] = {};
    const int arow = lane >> 2;
    const int akoff = (lane & 3) * 8;

    for (int k0 = 0; k0 < K; k0 += 32) {
        #pragma unroll
        for (int s = 0; s < 2; ++s) {
            const int c = 2 * wv + s;
            gload_lds16(&A[(size_t)(row0 + c * 16 + arow) * K + k0 + akoff], &Abuf[c * 512]);
            gload_lds16(&Bt[(size_t)(col0 + c * 16 + arow) * K + k0 + akoff], &Bbuf[c * 512]);
        }
        __syncthreads();

        bf16x8 a[4], b[4];
        #pragma unroll
        for (int i = 0; i < 4; ++i)
            a[i] = *(const bf16x8*)&Abuf[(wm + i * 16 + r0) * 32 + kb * 8];
        #pragma unroll
        for (int j = 0; j < 4; ++j)
            b[j] = *(const bf16x8*)&Bbuf[(wn + j * 16 + r0) * 32 + kb * 8];
        #pragma unroll
        for (int i = 0; i < 4; ++i)
            #pragma unroll
            for (int j = 0; j < 4; ++j)
                acc[i][j] = __builtin_amdgcn_mfma_f32_16x16x32_bf16(a[i], b[j], acc[i][j], 0, 0, 0);
        __syncthreads();
    }

    #pragma unroll
    for (int i = 0; i < 4; ++i) {
        #pragma unroll
        for (int j = 0; j < 4; ++j) {
            const int col = col0 + wn + j * 16 + r0;     // 0..1535
            const float bv = bias[col];
            const int region = col >> 9;                  // 0=q 1=k 2=v
            const int cc = col & 511;
            const int head = cc >> 6, d = cc & 63;
            const int l0 = row0 + wm + i * 16 + kb * 4;   // first of 4 rows
            const int b_ = l0 >> 10, l_ = l0 & 1023;      // 4 rows same b (l0%4==0, tiles aligned)
            if (region == 2) {
                // Vt: 4 consecutive l -> pack 8B store
                unsigned short pk[4];
                #pragma unroll
                for (int reg = 0; reg < 4; ++reg) pk[reg] = bfb(acc[i][j][reg] + bv);
                *(ushort4*)&Vtb[((size_t)(b_ * NUM_HEADS + head) * 64 + d) * SEQ_L + l_] =
                    make_ushort4(pk[0], pk[1], pk[2], pk[3]);
            } else {
                const float s = (region == 0) ? 0.125f : 1.0f;
                bf16* dst = (region == 0) ? Qb : Kb;
                #pragma unroll
                for (int reg = 0; reg < 4; ++reg) {
                    dst[((size_t)(b_ * NUM_HEADS + head) * SEQ_L + l_ + reg) * 64 + d] =
                        __float2bfloat16((acc[i][j][reg] + bv) * s);
                }
            }
        }
    }
}

// ------------------------------------------------------------------
// MFMA flash attention. Block = 256 threads (4 waves) on one (b,h),
// 64 q-rows (16/wave); 64-key chunks, online softmax.
// Qb scaled by 1/8. out: bf16 [B*L, 512] (head at h*64).
// ------------------------------------------------------------------
__global__ __launch_bounds__(256) void attn_mfma(
    const bf16* __restrict__ Qb, const bf16* __restrict__ Kb,
    const bf16* __restrict__ Vtb, const float* __restrict__ abias,
    const int* __restrict__ mask, bf16* __restrict__ out)
{
    const int bh = blockIdx.y;               // 0..63
    const int b = bh >> 3, h = bh & 7;
    const int q0 = blockIdx.x * 64;
    const int tid = threadIdx.x;
    const int wv = tid >> 6, lane = tid & 63;
    const int ql = lane & 15;                // q-local in wave tile
    const int hi = lane >> 4;                // 0..3

    __shared__ __align__(16) bf16 Ks[KVBLK * 64];    // swizzled [key][d]
    __shared__ __align__(16) bf16 Vs[64 * KVBLK];    // swizzled [d][key]
    __shared__ __align__(16) bf16 Ps[4][16 * 64];    // per-wave P [q][key], swizzled
    __shared__ float maskf[KVBLK];

    const int qrow = q0 + wv * 16 + ql;
    bf16x8 qf[2];
    #pragma unroll
    for (int kk = 0; kk < 2; ++kk)
        qf[kk] = *(const bf16x8*)&Qb[((size_t)bh * SEQ_L + qrow) * 64 + kk * 32 + hi * 8];

    f32x4 o[4] = {};                         // [d-group], rows q'=hi*4+reg
    float m = -1e30f, l = 0.f;

    const size_t bias_row = ((size_t)(b * NUM_HEADS + h) * SEQ_L + qrow) * SEQ_L;

    for (int k0 = 0; k0 < SEQ_L; k0 += KVBLK) {
        __syncthreads();   // prev chunk K/V consumed
        // stage K and Vt chunks (reg -> swizzled LDS)
        {
            const int r = tid >> 3;              // 0..31
            const int c8 = (tid & 7) * 8;
            #pragma unroll
            for (int it = 0; it < 2; ++it) {
                const int row = r + it * 32;
                bf16x8 kv = *(const bf16x8*)&Kb[((size_t)bh * SEQ_L + k0 + row) * 64 + c8];
                *(bf16x8*)&Ks[swz64(row * 64 + c8, row)] = kv;
                bf16x8 vv = *(const bf16x8*)&Vtb[((size_t)bh * 64 + row) * SEQ_L + k0 + c8];
                *(bf16x8*)&Vs[swz64(row * 64 + c8, row)] = vv;
            }
            if (tid < KVBLK)
                maskf[tid] = (mask[b * SEQ_L + k0 + tid] > 0) ? 0.f : -1e30f;
        }
        __syncthreads();

        // issue bias loads early
        f32x4 bias4[4];
        #pragma unroll
        for (int c = 0; c < 4; ++c)
            bias4[c] = *(const f32x4*)&abias[bias_row + k0 + c * 16 + hi * 4];

        // S^T = K . Q^T  (lane: q=ql, keys c*16+hi*4+reg)
        float p[4][4];
        #pragma unroll
        for (int c = 0; c < 4; ++c) {
            f32x4 sacc = {};
            #pragma unroll
            for (int kk = 0; kk < 2; ++kk) {
                const int row = c * 16 + ql;
                bf16x8 kf = *(const bf16x8*)&Ks[swz64(row * 64 + kk * 32 + hi * 8, row)];
                sacc = __builtin_amdgcn_mfma_f32_16x16x32_bf16(kf, qf[kk], sacc, 0, 0, 0);
            }
            const f32x4 mk = *(const f32x4*)&maskf[c * 16 + hi * 4];
            #pragma unroll
            for (int reg = 0; reg < 4; ++reg)
                p[c][reg] = sacc[reg] + bias4[c][reg] + mk[reg];
        }

        // online softmax over 64 keys of this chunk
        float mx = p[0][0];
        #pragma unroll
        for (int c = 0; c < 4; ++c)
            #pragma unroll
            for (int reg = 0; reg < 4; ++reg) mx = fmaxf(mx, p[c][reg]);
        mx = fmaxf(mx, __shfl_xor(mx, 16, 64));
        mx = fmaxf(mx, __shfl_xor(mx, 32, 64));

        const float mnew = fmaxf(m, mx);
        const float scale = __expf(m - mnew);
        m = mnew;
        float lsum = 0.f;
        #pragma unroll
        for (int c = 0; c < 4; ++c)
            #pragma unroll
            for (int reg = 0; reg < 4; ++reg) {
                const float pv = (p[c][reg] > -1e29f) ? __expf(p[c][reg] - mnew) : 0.f;
                p[c][reg] = pv;
                lsum += pv;
            }
        lsum += __shfl_xor(lsum, 16, 64);
        lsum += __shfl_xor(lsum, 32, 64);
        l = l * scale + lsum;

        // write P -> per-wave swizzled LDS tile (bf16 pairs)
        #pragma unroll
        for (int c = 0; c < 4; ++c)
            #pragma unroll
            for (int s2 = 0; s2 < 2; ++s2) {
                const int el = ql * 64 + c * 16 + hi * 4 + 2 * s2;
                const unsigned pk = (unsigned)bfb(p[c][2 * s2]) |
                                    ((unsigned)bfb(p[c][2 * s2 + 1]) << 16);
                *(unsigned*)&Ps[wv][swz64(el, ql)] = pk;
            }

        // rescale O (per-q scale via lane shuffle)
        #pragma unroll
        for (int reg = 0; reg < 4; ++reg) {
            const float sc_q = __shfl(scale, (lane & 48) | (hi * 4 + reg), 64);
            #pragma unroll
            for (int c2 = 0; c2 < 4; ++c2) o[c2][reg] *= sc_q;
        }

        // PV: O += P @ V
        #pragma unroll
        for (int kk = 0; kk < 2; ++kk) {
            bf16x8 pf = *(const bf16x8*)&Ps[wv][swz64(ql * 64 + kk * 32 + hi * 8, ql)];
            #pragma unroll
            for (int c2 = 0; c2 < 4; ++c2) {
                const int vrow = c2 * 16 + ql;
                bf16x8 vf = *(const bf16x8*)&Vs[swz64(vrow * 64 + kk * 32 + hi * 8, vrow)];
                o[c2] = __builtin_amdgcn_mfma_f32_16x16x32_bf16(pf, vf, o[c2], 0, 0, 0);
            }
        }
    }

    // final normalize + store
    const float invl = (l > 0.f) ? (1.0f / l) : 0.f;
    #pragma unroll
    for (int reg = 0; reg < 4; ++reg) {
        const float inv_q = __shfl(invl, (lane & 48) | (hi * 4 + reg), 64);
        const int row = q0 + wv * 16 + hi * 4 + reg;
        #pragma unroll
        for (int c2 = 0; c2 < 4; ++c2)
            out[((size_t)(b * SEQ_L + row)) * 512 + h * 64 + c2 * 16 + ql] =
                __float2bfloat16(o[c2][reg] * inv_q);
    }
}

// ------------------------------------------------------------------
// out = LayerNorm(X + Y) * gamma + beta; optional bf16 copy.
// ------------------------------------------------------------------
__global__ __launch_bounds__(256) void add_ln_kernel(
    const float* __restrict__ X, const float* __restrict__ Y,
    const float* __restrict__ gamma, const float* __restrict__ beta,
    float* __restrict__ out, bf16* __restrict__ outb)
{
    const int wave = threadIdx.x >> 6;
    const int lane = threadIdx.x & 63;
    const int row = blockIdx.x * 4 + wave;
    const float* xp = X + (size_t)row * 512 + lane * 8;
    const float* yp = Y + (size_t)row * 512 + lane * 8;

    float v[8];
    const float4 a0 = *(const float4*)xp;
    const float4 a1 = *(const float4*)(xp + 4);
    const float4 b0 = *(const float4*)yp;
    const float4 b1 = *(const float4*)(yp + 4);
    v[0] = a0.x + b0.x; v[1] = a0.y + b0.y; v[2] = a0.z + b0.z; v[3] = a0.w + b0.w;
    v[4] = a1.x + b1.x; v[5] = a1.y + b1.y; v[6] = a1.z + b1.z; v[7] = a1.w + b1.w;

    float s = 0.f, sq = 0.f;
    #pragma unroll
    for (int i = 0; i < 8; ++i) { s += v[i]; sq += v[i] * v[i]; }
    #pragma unroll
    for (int off = 1; off < 64; off <<= 1) {
        s += __shfl_xor(s, off, 64);
        sq += __shfl_xor(sq, off, 64);
    }
    const float mu = s * (1.f / 512.f);
    const float var = sq * (1.f / 512.f) - mu * mu;
    const float rstd = rsqrtf(var + EPS);

    const int c = lane * 8;
    const float4 g0 = *(const float4*)&gamma[c];
    const float4 g1 = *(const float4*)&gamma[c + 4];
    const float4 e0 = *(const float4*)&beta[c];
    const float4 e1 = *(const float4*)&beta[c + 4];
    float r[8];
    r[0] = (v[0] - mu) * rstd * g0.x + e0.x;
    r[1] = (v[1] - mu) * rstd * g0.y + e0.y;
    r[2] = (v[2] - mu) * rstd * g0.z + e0.z;
    r[3] = (v[3] - mu) * rstd * g0.w + e0.w;
    r[4] = (v[4] - mu) * rstd * g1.x + e1.x;
    r[5] = (v[5] - mu) * rstd * g1.y + e1.y;
    r[6] = (v[6] - mu) * rstd * g1.z + e1.z;
    r[7] = (v[7] - mu) * rstd * g1.w + e1.w;

    float* op = out + (size_t)row * 512 + c;
    *(float4*)op = make_float4(r[0], r[1], r[2], r[3]);
    *(float4*)(op + 4) = make_float4(r[4], r[5], r[6], r[7]);
    if (outb) {
        bf16* ob = outb + (size_t)row * 512 + c;
        #pragma unroll
        for (int i = 0; i < 8; ++i) ob[i] = __float2bfloat16(r[i]);
    }
}

// ------------------------------------------------------------------
extern "C" void kernel_launch(void* const* d_in, const int* in_sizes, int n_in,
                              void* d_out, int out_size, void* d_ws, size_t ws_size,
                              hipStream_t stream)
{
    const float* h    = (const float*)d_in[0];
    const float* ab   = (const float*)d_in[1];
    const int*   mask = (const int*)d_in[2];
    const float* Wqkv = (const float*)d_in[3];
    const float* bqkv = (const float*)d_in[4];
    const float* Wo   = (const float*)d_in[5];
    const float* bo   = (const float*)d_in[6];
    const float* W1   = (const float*)d_in[7];
    const float* b1   = (const float*)d_in[8];
    const float* W2   = (const float*)d_in[9];
    const float* b2   = (const float*)d_in[10];
    const float* g1   = (const float*)d_in[11];
    const float* be1  = (const float*)d_in[12];
    const float* g2   = (const float*)d_in[13];
    const float* be2  = (const float*)d_in[14];
    float* out = (float*)d_out;
    char* ws = (char*)d_ws;

    const int M = 8 * 1024;
    const size_t MB = 1024 * 1024;

    // workspace layout (liveness-based reuse, peak 87MB):
    bf16*  hb   = (bf16*)(ws + 0 * MB);     // [M,512]    8MB (dead after QKV)
    bf16*  Wtq  = (bf16*)(ws + 8 * MB);     // [1536,512] 1.5MB
    bf16*  Wto  = (bf16*)(ws + 10 * MB);    // [512,512]  0.5MB
    bf16*  Wt1  = (bf16*)(ws + 11 * MB);    // [2048,512] 2MB
    bf16*  Wt2  = (bf16*)(ws + 13 * MB);    // [512,2048] 2MB
    bf16*  Qb   = (bf16*)(ws + 15 * MB);    // [64,1024,64] 8MB
    bf16*  Kb   = (bf16*)(ws + 23 * MB);    // 8MB
    bf16*  Vtb  = (bf16*)(ws + 31 * MB);    // [64,64,1024] 8MB
    bf16*  aob  = (bf16*)(ws + 39 * MB);    // [M,512]    8MB (dead after proj)
    float* proj = (float*)(ws + 47 * MB);   // [M,512]   16MB (dead after LN1)
    float* h1   = (float*)(ws + 63 * MB);   // [M,512]   16MB
    bf16*  h1b  = (bf16*)(ws + 79 * MB);    // [M,512]    8MB
    bf16*  ffb  = (bf16*)(ws + 15 * MB);    // [M,2048]  32MB (reuses QKV bufs)
    float* f2   = (float*)(ws + 47 * MB);   // [M,512]   16MB (reuses proj)

    // 0. converts / weight transposes
    f32_to_bf16_kernel<<<dim3(M * 512 / 1024), 256, 0, stream>>>(h, hb, M * 512);
    transpose_w<<<dim3(1536 / 32, 512 / 32), 256, 0, stream>>>(Wqkv, Wtq, 512, 1536);
    transpose_w<<<dim3(512 / 32, 512 / 32), 256, 0, stream>>>(Wo, Wto, 512, 512);
    transpose_w<<<dim3(2048 / 32, 512 / 32), 256, 0, stream>>>(W1, Wt1, 512, 2048);
    transpose_w<<<dim3(512 / 32, 2048 / 32), 256, 0, stream>>>(W2, Wt2, 2048, 512);

    // 1. QKV GEMM with split epilogue
    gemm_qkv<<<dim3(1536 / 128, M / 128), 256, 0, stream>>>(hb, Wtq, bqkv, Qb, Kb, Vtb, M, 1536, 512);
    // 2. MFMA flash attention
    attn_mfma<<<dim3(SEQ_L / 64, 64), 256, 0, stream>>>(Qb, Kb, Vtb, ab, mask, aob);
    // 3. proj
    gemm_bf16<<<dim3(512 / 128, M / 128), 256, 0, stream>>>(aob, Wto, bo, proj, nullptr, M, 512, 512, 0);
    // 4. h1 = LN(h + proj)
    add_ln_kernel<<<dim3(M / 4), 256, 0, stream>>>(h, proj, g1, be1, h1, h1b);
    // 5. ff = relu(h1 @ W1 + b1)
    gemm_bf16<<<dim3(2048 / 128, M / 128), 256, 0, stream>>>(h1b, Wt1, b1, nullptr, ffb, M, 2048, 512, 1);
    // 6. f2 = ff @ W2 + b2
    gemm_bf16<<<dim3(512 / 128, M / 128), 256, 0, stream>>>(ffb, Wt2, b2, f2, nullptr, M, 512, 2048, 0);
    // 7. out = LN(h1 + f2)
    add_ln_kernel<<<dim3(M / 4), 256, 0, stream>>>(h1, f2, g2, be2, out, nullptr);
}